// Round 4
// baseline (97.012 us; speedup 1.0000x reference)
//
#include <hip/hip_runtime.h>

#define NQ   5
#define QD   6
#define NGEN 4
#define NW   (NGEN * QD * NQ)   // 120 weight angles

typedef float f32x4 __attribute__((ext_vector_type(4)));
typedef short short8 __attribute__((ext_vector_type(8)));   // 8 bf16 (4 VGPRs)

__device__ inline unsigned short f2bf_rne(float f) {
    unsigned u = __float_as_uint(f);
    u += 0x7FFFu + ((u >> 16) & 1u);
    return (unsigned short)(u >> 16);
}
__device__ inline float bf2f(unsigned short h) {
    return __uint_as_float(((unsigned)h) << 16);
}

// ---------------------------------------------------------------------------
// Kernel A: simulate the batch-uniform weight circuit for all 32 basis states
// per generator, then emit the MFMA B-operand fragments directly:
// B[k][n] for tile g, with n = channel j (0..15), k = basis t (0..31).
// Fragment order: lane l of apply needs elements M[g][j=l&15][k=(l>>4)*8 + kk]
// -> flat bf16 index ((g*4 + (t>>3))*16 + j)*8 + (t&7).
// Emitted as hi/lo bf16 pair (3-term split compensation).
// ---------------------------------------------------------------------------
__global__ __launch_bounds__(128) void qsrgan_build(
    const float* __restrict__ qp,      // (4,30)
    unsigned short* __restrict__ Bh,   // 2048 bf16 (4 KB)
    unsigned short* __restrict__ Bl)   // 2048 bf16 (4 KB)
{
    __shared__ float cw[NW];
    __shared__ float sw[NW];
    const int t = threadIdx.x;
    if (t < NW) {
        float sv, cv;
        __sincosf(0.5f * qp[t], &sv, &cv);
        cw[t] = cv;
        sw[t] = sv;
    }
    __syncthreads();

    const int g = t >> 5;
    const int basis = t & 31;

    float st[32];
#pragma unroll
    for (int i = 0; i < 32; ++i) st[i] = (i == basis) ? 1.0f : 0.0f;

    for (int d = 0; d < QD; ++d) {
        const int base = g * (QD * NQ) + d * NQ;
#pragma unroll
        for (int w = 0; w < NQ; ++w) {
            const float cc = cw[base + w];
            const float ss = sw[base + w];
            const int stride = 1 << (4 - w);
#pragma unroll
            for (int i = 0; i < 32; ++i) {
                if (i & stride) continue;
                float a0 = st[i];
                float a1 = st[i + stride];
                st[i]          = cc * a0 - ss * a1;
                st[i + stride] = ss * a0 + cc * a1;
            }
        }
#pragma unroll
        for (int i = 0; i < 32; ++i) {
            int flips = 0;
#pragma unroll
            for (int w = 0; w < NQ - 1; ++w) {
                const int m = (1 << (4 - w)) | (1 << (3 - w));
                flips ^= ((i & m) == m) ? 1 : 0;
            }
            if (flips) st[i] = -st[i];
        }
    }

    // st[j] = M[g][j][basis]
#pragma unroll
    for (int j = 0; j < 16; ++j) {
        const float v = st[j];
        const unsigned short hi = f2bf_rne(v);
        const float r = v - bf2f(hi);
        const unsigned short lo = f2bf_rne(r);
        const int idx = ((g * 4 + (basis >> 3)) * 16 + j) * 8 + (basis & 7);
        Bh[idx] = hi;
        Bl[idx] = lo;
    }
}

// ---------------------------------------------------------------------------
// Kernel B: wave = 16 samples, block = 4 waves = 64 samples.
// Outpre(16x64) = Init(16x32) @ M^T(32x64) via 4 tiles (one per generator) of
// mfma_f32_16x16x32_bf16, 3-term bf16 split: ah*bh + al*bh + ah*bl.
// A-frag: lane l holds Init[m = l&15][k = (l>>4)*8 + j]  (j=0..7)
// C/D:    lane l holds D[row = (l>>4)*4 + r][col = l&15]
// Epilogue: p = d^2, max over the 16 channel-lanes (shfl_xor 1/2/4/8),
// scale, LDS transpose, coalesced float4 store.
// ---------------------------------------------------------------------------
__global__ __launch_bounds__(256, 4) void qsrgan_apply(
    const float* __restrict__ inp,          // (B,16)
    const unsigned short* __restrict__ Bh,  // B-frags hi
    const unsigned short* __restrict__ Bl,  // B-frags lo
    float* __restrict__ out,                // (B,64)
    int B)
{
    __shared__ float pl[64 * 66];   // [channel][sample], pad 66

    const int t    = threadIdx.x;
    const int lane = t & 63;
    const int w    = t >> 6;       // wave id = sample-block within the 64
    const int q    = lane >> 4;    // k-chunk (A) / row-group (C)
    const int c    = lane & 15;    // sample (A) / channel (B,C)
    const int s0   = blockIdx.x * 64;

    // ---- A-side sample load (lanes 16..63 redundantly reload, L1-hot) ----
    const int bsmp = min(s0 + w * 16 + c, B - 1);
    const float4 x = *reinterpret_cast<const float4*>(inp + (size_t)bsmp * 16);

    // ---- B fragments: wave-identical 16B vector loads, L2-resident ----
    short8 bh[4], bl[4];
    const short8* gh = reinterpret_cast<const short8*>(Bh);
    const short8* gl = reinterpret_cast<const short8*>(Bl);
#pragma unroll
    for (int g = 0; g < 4; ++g) {
        bh[g] = gh[g * 64 + lane];
        bl[g] = gl[g * 64 + lane];
    }

    // ---- init fragment: 8 elements k = q*8 + j ----
    float n[5];
    n[0] = x.x;
    n[1] = 0.75f * x.x + 0.25f * x.y;
    n[2] = 0.25f * x.x + 0.75f * x.y;
    n[3] = 0.75f * x.y + 0.25f * x.z;
    n[4] = 0.25f * x.y + 0.75f * x.z;
    float cn[5], sn[5];
#pragma unroll
    for (int i = 0; i < 5; ++i) {
        sn[i] = __sinf(0.5f * n[i]);
        cn[i] = __cosf(0.5f * n[i]);
    }
    // k bits: b0=k>>4 (wire0), b1 (wire1), b2 (wire2), b3 (wire3), b4=k&1 (wire4)
    // k = q*8+j -> b0b1 = q, b2b3b4 = j
    const float U = ((q >> 1) ? sn[0] : cn[0]) * ((q & 1) ? sn[1] : cn[1]);
    float w34[4];
    w34[0] = cn[3] * cn[4];
    w34[1] = cn[3] * sn[4];
    w34[2] = sn[3] * cn[4];
    w34[3] = sn[3] * sn[4];

    short8 ah, al;
#pragma unroll
    for (int j = 0; j < 8; ++j) {
        const float a = U * ((j >> 2) ? sn[2] : cn[2]) * w34[j & 3];
        const unsigned short hi = f2bf_rne(a);
        const float r = a - bf2f(hi);
        ah[j] = (short)hi;
        al[j] = (short)f2bf_rne(r);
    }

    // ---- 4 generator tiles x 3-term split ----
    f32x4 acc[4];
#pragma unroll
    for (int g = 0; g < 4; ++g) {
        f32x4 a0 = {0.0f, 0.0f, 0.0f, 0.0f};
        a0 = __builtin_amdgcn_mfma_f32_16x16x32_bf16(ah, bh[g], a0, 0, 0, 0);
        a0 = __builtin_amdgcn_mfma_f32_16x16x32_bf16(al, bh[g], a0, 0, 0, 0);
        a0 = __builtin_amdgcn_mfma_f32_16x16x32_bf16(ah, bl[g], a0, 0, 0, 0);
        acc[g] = a0;
    }

    // ---- epilogue: square, per-(sample,gen) max over 16 channel-lanes ----
#pragma unroll
    for (int g = 0; g < 4; ++g) {
#pragma unroll
        for (int r = 0; r < 4; ++r) {
            const float d = acc[g][r];
            float p = d * d;
            float m = p;
            m = fmaxf(m, __shfl_xor(m, 1));
            m = fmaxf(m, __shfl_xor(m, 2));
            m = fmaxf(m, __shfl_xor(m, 4));
            m = fmaxf(m, __shfl_xor(m, 8));
            const float v = p * (1.0f / m);
            // sample column = w*16 + q*4 + r; channel row = g*16 + c
            pl[(g * 16 + c) * 66 + (w * 16 + q * 4 + r)] = v;
        }
    }

    __syncthreads();

    // ---- coalesced write-out: 64 samples x 64 floats = 1024 float4 ----
    const size_t base = (size_t)s0 * 64;
    float4* __restrict__ o4 = reinterpret_cast<float4*>(out + base);
#pragma unroll
    for (int i = 0; i < 4; ++i) {
        const int qq   = t + i * 256;
        const int srow = qq >> 4;
        const int c0   = (qq & 15) << 2;
        if (s0 + srow < B) {
            float4 v;
            v.x = pl[(c0 + 0) * 66 + srow];
            v.y = pl[(c0 + 1) * 66 + srow];
            v.z = pl[(c0 + 2) * 66 + srow];
            v.w = pl[(c0 + 3) * 66 + srow];
            o4[qq] = v;
        }
    }
}

extern "C" void kernel_launch(void* const* d_in, const int* in_sizes, int n_in,
                              void* d_out, int out_size, void* d_ws, size_t ws_size,
                              hipStream_t stream) {
    const float* inp = (const float*)d_in[0];
    const float* qp  = (const float*)d_in[1];
    float* out = (float*)d_out;
    unsigned short* Bh = (unsigned short*)d_ws;          // 4 KB
    unsigned short* Bl = (unsigned short*)d_ws + 2048;   // 4 KB
    const int B = in_sizes[0] / 16;

    qsrgan_build<<<1, 128, 0, stream>>>(qp, Bh, Bl);
    const int blocks = (B + 63) / 64;
    qsrgan_apply<<<blocks, 256, 0, stream>>>(inp, Bh, Bl, out, B);
}

// Round 5
// 91.828 us; speedup vs baseline: 1.0565x; 1.0565x over previous
//
#include <hip/hip_runtime.h>

#define NQ   5
#define QD   6
#define NGEN 4
#define NW   (NGEN * QD * NQ)   // 120 weight angles

typedef float f32x4 __attribute__((ext_vector_type(4)));
typedef short short8 __attribute__((ext_vector_type(8)));   // 8 bf16 (4 VGPRs)

__device__ inline unsigned short f2bf_rne(float f) {
    unsigned u = __float_as_uint(f);
    u += 0x7FFFu + ((u >> 16) & 1u);
    return (unsigned short)(u >> 16);
}
__device__ inline float bf2f(unsigned short h) {
    return __uint_as_float(((unsigned)h) << 16);
}

// ---------------------------------------------------------------------------
// Kernel A (unchanged from r4): simulate the batch-uniform weight circuit for
// all 32 basis states per generator, emit MFMA fragments of M[g][ch][k]:
// fragment vector (g*64 + lane), element kk, with lane = (k>>3)*16 + ch,
// kk = k&7.  This layout serves as the A-operand (lane&15 = m = channel,
// (lane>>4)*8+kk = k) of the transposed product M . Init^T.
// hi/lo bf16 pair for the 3-term split.
// ---------------------------------------------------------------------------
__global__ __launch_bounds__(128) void qsrgan_build(
    const float* __restrict__ qp,      // (4,30)
    unsigned short* __restrict__ Mh,   // 2048 bf16 (4 KB)
    unsigned short* __restrict__ Ml)   // 2048 bf16 (4 KB)
{
    __shared__ float cw[NW];
    __shared__ float sw[NW];
    const int t = threadIdx.x;
    if (t < NW) {
        float sv, cv;
        __sincosf(0.5f * qp[t], &sv, &cv);
        cw[t] = cv;
        sw[t] = sv;
    }
    __syncthreads();

    const int g = t >> 5;
    const int basis = t & 31;

    float st[32];
#pragma unroll
    for (int i = 0; i < 32; ++i) st[i] = (i == basis) ? 1.0f : 0.0f;

    for (int d = 0; d < QD; ++d) {
        const int base = g * (QD * NQ) + d * NQ;
#pragma unroll
        for (int w = 0; w < NQ; ++w) {
            const float cc = cw[base + w];
            const float ss = sw[base + w];
            const int stride = 1 << (4 - w);
#pragma unroll
            for (int i = 0; i < 32; ++i) {
                if (i & stride) continue;
                float a0 = st[i];
                float a1 = st[i + stride];
                st[i]          = cc * a0 - ss * a1;
                st[i + stride] = ss * a0 + cc * a1;
            }
        }
#pragma unroll
        for (int i = 0; i < 32; ++i) {
            int flips = 0;
#pragma unroll
            for (int w = 0; w < NQ - 1; ++w) {
                const int m = (1 << (4 - w)) | (1 << (3 - w));
                flips ^= ((i & m) == m) ? 1 : 0;
            }
            if (flips) st[i] = -st[i];
        }
    }

    // st[j] = M[g][ch=j][k=basis]
#pragma unroll
    for (int j = 0; j < 16; ++j) {
        const float v = st[j];
        const unsigned short hi = f2bf_rne(v);
        const float r = v - bf2f(hi);
        const unsigned short lo = f2bf_rne(r);
        const int idx = ((g * 4 + (basis >> 3)) * 16 + j) * 8 + (basis & 7);
        Mh[idx] = hi;
        Ml[idx] = lo;
    }
}

// ---------------------------------------------------------------------------
// Kernel B: wave = 16 samples, block = 4 waves = 64 samples. Transposed GEMM:
// D^T(ch x s) = M(16x32) @ Init^T(32x16) per generator tile g, so lane l /
// reg r holds (channel g*16 + (l>>4)*4 + r, sample l&15) -> 4 CONSECUTIVE
// channels of one sample = one float4 store. Max over the 16 channels of
// (sample,g) = 3 local fmax + shfl_xor(16) + shfl_xor(32).
// No LDS, no barrier, 8 DS ops/thread total (was 96/wave-row in r4).
// ---------------------------------------------------------------------------
__global__ __launch_bounds__(256, 4) void qsrgan_apply(
    const float* __restrict__ inp,          // (B,16)
    const unsigned short* __restrict__ Mh,  // M-frags hi
    const unsigned short* __restrict__ Ml,  // M-frags lo
    float* __restrict__ out,                // (B,64)
    int B)
{
    const int t    = threadIdx.x;
    const int lane = t & 63;
    const int w    = t >> 6;       // wave id -> 16-sample slice
    const int q    = lane >> 4;    // k-chunk (B-frag) / channel-quad (C/D)
    const int c    = lane & 15;    // sample
    const int s0   = blockIdx.x * 64;

    // ---- sample load: 16 distinct rows per wave, 4x lane redundancy ----
    const int bsmp = min(s0 + w * 16 + c, B - 1);
    const float4 x = *reinterpret_cast<const float4*>(inp + (size_t)bsmp * 16);

    // ---- M fragments (A-operand): wave-identical b128 loads, L2-resident --
    short8 mh[4], ml[4];
    const short8* gh = reinterpret_cast<const short8*>(Mh);
    const short8* gl = reinterpret_cast<const short8*>(Ml);
#pragma unroll
    for (int g = 0; g < 4; ++g) {
        mh[g] = gh[g * 64 + lane];
        ml[g] = gl[g * 64 + lane];
    }

    // ---- init fragment (B-operand): lane holds init_{sample c}[k=q*8+j] ---
    float n[5];
    n[0] = x.x;
    n[1] = 0.75f * x.x + 0.25f * x.y;
    n[2] = 0.25f * x.x + 0.75f * x.y;
    n[3] = 0.75f * x.y + 0.25f * x.z;
    n[4] = 0.25f * x.y + 0.75f * x.z;
    float cn[5], sn[5];
#pragma unroll
    for (int i = 0; i < 5; ++i) __sincosf(0.5f * n[i], &sn[i], &cn[i]);

    // k bits: wire0 = q>>1, wire1 = q&1, wire2 = j>>2, wires3/4 = j&3
    const float U = ((q >> 1) ? sn[0] : cn[0]) * ((q & 1) ? sn[1] : cn[1]);
    float w34[4];
    w34[0] = cn[3] * cn[4];
    w34[1] = cn[3] * sn[4];
    w34[2] = sn[3] * cn[4];
    w34[3] = sn[3] * sn[4];

    short8 ih, il;
#pragma unroll
    for (int j = 0; j < 8; ++j) {
        const float a = U * ((j >> 2) ? sn[2] : cn[2]) * w34[j & 3];
        const unsigned short hi = f2bf_rne(a);
        const float r = a - bf2f(hi);
        ih[j] = (short)hi;
        il[j] = (short)f2bf_rne(r);
    }

    // ---- 4 generator tiles, 3-term bf16 split ----
    f32x4 acc[4];
#pragma unroll
    for (int g = 0; g < 4; ++g) {
        f32x4 a0 = {0.0f, 0.0f, 0.0f, 0.0f};
        a0 = __builtin_amdgcn_mfma_f32_16x16x32_bf16(mh[g], ih, a0, 0, 0, 0);
        a0 = __builtin_amdgcn_mfma_f32_16x16x32_bf16(ml[g], ih, a0, 0, 0, 0);
        a0 = __builtin_amdgcn_mfma_f32_16x16x32_bf16(mh[g], il, a0, 0, 0, 0);
        acc[g] = a0;
    }

    // ---- epilogue: square, max over 16 channels (3 fmax + 2 shfl), store --
    float* __restrict__ orow = out + (size_t)bsmp * 64;
#pragma unroll
    for (int g = 0; g < 4; ++g) {
        float p0 = acc[g][0] * acc[g][0];
        float p1 = acc[g][1] * acc[g][1];
        float p2 = acc[g][2] * acc[g][2];
        float p3 = acc[g][3] * acc[g][3];
        float m = fmaxf(fmaxf(p0, p1), fmaxf(p2, p3));
        m = fmaxf(m, __shfl_xor(m, 16));
        m = fmaxf(m, __shfl_xor(m, 32));
        const float inv = 1.0f / m;
        float4 v = make_float4(p0 * inv, p1 * inv, p2 * inv, p3 * inv);
        *reinterpret_cast<float4*>(orow + g * 16 + q * 4) = v;
    }
}

extern "C" void kernel_launch(void* const* d_in, const int* in_sizes, int n_in,
                              void* d_out, int out_size, void* d_ws, size_t ws_size,
                              hipStream_t stream) {
    const float* inp = (const float*)d_in[0];
    const float* qp  = (const float*)d_in[1];
    float* out = (float*)d_out;
    unsigned short* Mh = (unsigned short*)d_ws;          // 4 KB
    unsigned short* Ml = (unsigned short*)d_ws + 2048;   // 4 KB
    const int B = in_sizes[0] / 16;

    qsrgan_build<<<1, 128, 0, stream>>>(qp, Mh, Ml);
    const int blocks = (B + 63) / 64;
    qsrgan_apply<<<blocks, 256, 0, stream>>>(inp, Mh, Ml, out, B);
}

// Round 6
// 90.261 us; speedup vs baseline: 1.0748x; 1.0174x over previous
//
#include <hip/hip_runtime.h>

#define NQ   5
#define QD   6
#define NGEN 4
#define NW   (NGEN * QD * NQ)   // 120 weight angles

typedef float  f32x16 __attribute__((ext_vector_type(16)));
typedef short  short8 __attribute__((ext_vector_type(8)));   // 8 bf16

__device__ inline unsigned short f2bf_rne(float f) {
    unsigned u = __float_as_uint(f);
    u += 0x7FFFu + ((u >> 16) & 1u);
    return (unsigned short)(u >> 16);
}
__device__ inline float bf2f(unsigned short h) {
    return __uint_as_float(((unsigned)h) << 16);
}

// ---------------------------------------------------------------------------
// Kernel A: simulate the batch-uniform weight circuit for the 32 basis states
// per generator; emit A-operand fragments for mfma_f32_32x32x16_bf16 with the
// channel rows of generators (2T, 2T+1) stacked into one 32-row tile:
//   A[m = (g&1)*16 + ch][k = basis],  tile T = g>>1, k-step S = basis>>4
//   lane = m + 32*((basis>>3)&1), elem j = basis&7
//   flat bf16 index = ((T*2 + S)*64 + lane)*8 + j
// hi/lo bf16 pair for the 3-term precision split.
// ---------------------------------------------------------------------------
__global__ __launch_bounds__(128) void qsrgan_build(
    const float* __restrict__ qp,      // (4,30)
    unsigned short* __restrict__ Mh,   // 2048 bf16 (4 KB)
    unsigned short* __restrict__ Ml)   // 2048 bf16 (4 KB)
{
    __shared__ float cw[NW];
    __shared__ float sw[NW];
    const int t = threadIdx.x;
    if (t < NW) {
        float sv, cv;
        __sincosf(0.5f * qp[t], &sv, &cv);
        cw[t] = cv;
        sw[t] = sv;
    }
    __syncthreads();

    const int g = t >> 5;
    const int basis = t & 31;

    float st[32];
#pragma unroll
    for (int i = 0; i < 32; ++i) st[i] = (i == basis) ? 1.0f : 0.0f;

    for (int d = 0; d < QD; ++d) {
        const int base = g * (QD * NQ) + d * NQ;
#pragma unroll
        for (int w = 0; w < NQ; ++w) {
            const float cc = cw[base + w];
            const float ss = sw[base + w];
            const int stride = 1 << (4 - w);
#pragma unroll
            for (int i = 0; i < 32; ++i) {
                if (i & stride) continue;
                float a0 = st[i];
                float a1 = st[i + stride];
                st[i]          = cc * a0 - ss * a1;
                st[i + stride] = ss * a0 + cc * a1;
            }
        }
#pragma unroll
        for (int i = 0; i < 32; ++i) {
            int flips = 0;
#pragma unroll
            for (int w = 0; w < NQ - 1; ++w) {
                const int m = (1 << (4 - w)) | (1 << (3 - w));
                flips ^= ((i & m) == m) ? 1 : 0;
            }
            if (flips) st[i] = -st[i];
        }
    }

    // st[ch] = M[g][ch][basis]
    const int T = g >> 1;
    const int S = basis >> 4;
    const int lane_h = 32 * ((basis >> 3) & 1);
    const int j = basis & 7;
#pragma unroll
    for (int ch = 0; ch < 16; ++ch) {
        const float v = st[ch];
        const unsigned short hi = f2bf_rne(v);
        const float r = v - bf2f(hi);
        const unsigned short lo = f2bf_rne(r);
        const int m   = (g & 1) * 16 + ch;
        const int idx = (((T * 2 + S) * 64) + (m + lane_h)) * 8 + j;
        Mh[idx] = hi;
        Ml[idx] = lo;
    }
}

// ---------------------------------------------------------------------------
// Kernel B: wave = 32 samples, block = 4 waves = 128 samples.
// Per generator-pair tile T: D^T(32ch x 32s) = A(32x32) @ Init^T(32x32) via
// 2 k-steps of mfma_f32_32x32x16_bf16, 3-term bf16 split (6 MFMA/tile).
// C/D: col = lane&31 = sample, row = (reg&3) + 8*(reg>>2) + 4*(lane>>5).
// Regs 0-7 = generator 2T (rows 0-15), regs 8-15 = generator 2T+1.
// Max over a generator's 16 channels = 7 local fmax + shfl_xor(32).
// Stores: reg-quads are 4 consecutive channels -> float4; lanes l, l^32 are
// the same sample 16 B apart -> 32 B contiguous segments per instruction.
// ---------------------------------------------------------------------------
__global__ __launch_bounds__(256, 4) void qsrgan_apply(
    const float* __restrict__ inp,          // (B,16)
    const unsigned short* __restrict__ Mh,
    const unsigned short* __restrict__ Ml,
    float* __restrict__ out,                // (B,64)
    int B)
{
    const int t    = threadIdx.x;
    const int lane = t & 63;
    const int w    = t >> 6;
    const int s    = lane & 31;    // sample within wave tile
    const int h    = lane >> 5;    // half: k-offset (B) / row-offset (C/D)
    const int s0   = blockIdx.x * 128 + w * 32;

    // ---- sample load: 32 distinct rows per wave, 2x lane redundancy ----
    const int bsmp = min(s0 + s, B - 1);
    const float4 x = *reinterpret_cast<const float4*>(inp + (size_t)bsmp * 16);

    // ---- A fragments: wave-identical b128 loads, L2-resident ----
    short8 mh[4], ml[4];                    // index = T*2 + S
    const short8* gh = reinterpret_cast<const short8*>(Mh);
    const short8* gl = reinterpret_cast<const short8*>(Ml);
#pragma unroll
    for (int i = 0; i < 4; ++i) {
        mh[i] = gh[i * 64 + lane];
        ml[i] = gl[i * 64 + lane];
    }

    // ---- init fragment (B-operand): lane holds init_{sample s}[k] for
    //      k = S*16 + h*8 + j. Wire bits of k: w0=S, w1=h, w2=j>>2,
    //      w3=(j>>1)&1, w4=j&1.
    float n[5];
    n[0] = x.x;
    n[1] = 0.75f * x.x + 0.25f * x.y;
    n[2] = 0.25f * x.x + 0.75f * x.y;
    n[3] = 0.75f * x.y + 0.25f * x.z;
    n[4] = 0.25f * x.y + 0.75f * x.z;
    float cn[5], sn[5];
#pragma unroll
    for (int i = 0; i < 5; ++i) __sincosf(0.5f * n[i], &sn[i], &cn[i]);

    float w34[4];
    w34[0] = cn[3] * cn[4];
    w34[1] = cn[3] * sn[4];
    w34[2] = sn[3] * cn[4];
    w34[3] = sn[3] * sn[4];
    float w234[8];
#pragma unroll
    for (int j = 0; j < 8; ++j)
        w234[j] = ((j >> 2) ? sn[2] : cn[2]) * w34[j & 3];

    const float w1 = h ? sn[1] : cn[1];
    const float pre[2] = { cn[0] * w1, sn[0] * w1 };

    short8 ih[2], il[2];
#pragma unroll
    for (int S = 0; S < 2; ++S) {
#pragma unroll
        for (int j = 0; j < 8; ++j) {
            const float a = pre[S] * w234[j];
            const unsigned short hi = f2bf_rne(a);
            const float r = a - bf2f(hi);
            ih[S][j] = (short)hi;
            il[S][j] = (short)f2bf_rne(r);
        }
    }

    // ---- 2 tiles x 2 k-steps x 3-term split ----
    f32x16 acc[2];
#pragma unroll
    for (int T = 0; T < 2; ++T) {
        f32x16 a;
#pragma unroll
        for (int r = 0; r < 16; ++r) a[r] = 0.0f;
#pragma unroll
        for (int S = 0; S < 2; ++S) {
            const int i = T * 2 + S;
            a = __builtin_amdgcn_mfma_f32_32x32x16_bf16(mh[i], ih[S], a, 0, 0, 0);
            a = __builtin_amdgcn_mfma_f32_32x32x16_bf16(ml[i], ih[S], a, 0, 0, 0);
            a = __builtin_amdgcn_mfma_f32_32x32x16_bf16(mh[i], il[S], a, 0, 0, 0);
        }
        acc[T] = a;
    }

    // ---- epilogue ----
    float* __restrict__ orow = out + (size_t)bsmp * 64;
#pragma unroll
    for (int T = 0; T < 2; ++T) {
        float p[16];
#pragma unroll
        for (int r = 0; r < 16; ++r) p[r] = acc[T][r] * acc[T][r];

        float mlo = fmaxf(fmaxf(fmaxf(p[0], p[1]), fmaxf(p[2], p[3])),
                          fmaxf(fmaxf(p[4], p[5]), fmaxf(p[6], p[7])));
        float mhi = fmaxf(fmaxf(fmaxf(p[8], p[9]), fmaxf(p[10], p[11])),
                          fmaxf(fmaxf(p[12], p[13]), fmaxf(p[14], p[15])));
        mlo = fmaxf(mlo, __shfl_xor(mlo, 32));
        mhi = fmaxf(mhi, __shfl_xor(mhi, 32));
        const float vlo = 1.0f / mlo;
        const float vhi = 1.0f / mhi;

        // channel base for reg-quad q is T*32 + {0,8,16,24}[q] + 4h
        float4 v0 = make_float4(p[0] * vlo, p[1] * vlo, p[2] * vlo, p[3] * vlo);
        float4 v1 = make_float4(p[4] * vlo, p[5] * vlo, p[6] * vlo, p[7] * vlo);
        float4 v2 = make_float4(p[8] * vhi, p[9] * vhi, p[10] * vhi, p[11] * vhi);
        float4 v3 = make_float4(p[12] * vhi, p[13] * vhi, p[14] * vhi, p[15] * vhi);
        float* base = orow + T * 32 + 4 * h;
        *reinterpret_cast<float4*>(base +  0) = v0;
        *reinterpret_cast<float4*>(base +  8) = v1;
        *reinterpret_cast<float4*>(base + 16) = v2;
        *reinterpret_cast<float4*>(base + 24) = v3;
    }
}

extern "C" void kernel_launch(void* const* d_in, const int* in_sizes, int n_in,
                              void* d_out, int out_size, void* d_ws, size_t ws_size,
                              hipStream_t stream) {
    const float* inp = (const float*)d_in[0];
    const float* qp  = (const float*)d_in[1];
    float* out = (float*)d_out;
    unsigned short* Mh = (unsigned short*)d_ws;          // 4 KB
    unsigned short* Ml = (unsigned short*)d_ws + 2048;   // 4 KB
    const int B = in_sizes[0] / 16;

    qsrgan_build<<<1, 128, 0, stream>>>(qp, Mh, Ml);
    const int blocks = (B + 127) / 128;
    qsrgan_apply<<<blocks, 256, 0, stream>>>(inp, Mh, Ml, out, B);
}